// Round 1
// baseline (290.203 us; speedup 1.0000x reference)
//
#include <hip/hip_runtime.h>
#include <hip/hip_bf16.h>

// Problem constants (fixed shapes from reference)
#define TDIM 8192
#define BDIM 16
#define HDIM 256
#define PHL  513          // ph_length
#define PADL 515          // L + 2 pad rows (one each side) for K=3 'same' conv
#define MROWS (BDIM*PHL)  // 8208 (b,l) rows

typedef __attribute__((ext_vector_type(8))) short  short8;
typedef __attribute__((ext_vector_type(4))) float  floatx4;

__device__ __forceinline__ float sigmoidf_(float x){ return 1.0f/(1.0f+__expf(-x)); }

// block (256 threads) sum-reduce, result broadcast to all threads
__device__ __forceinline__ float blk_reduce(float v, float* red){
  #pragma unroll
  for (int off=32; off>0; off>>=1) v += __shfl_xor(v, off, 64);
  int w = threadIdx.x>>6;
  __syncthreads();                       // protect red[] reuse across calls
  if ((threadIdx.x&63)==0) red[w]=v;
  __syncthreads();
  return red[0]+red[1]+red[2]+red[3];
}

// ---------------- K0: per-batch inclusive scan of ph_bd -> mel2ph ----------------
__global__ __launch_bounds__(256) void k_scan(const int* __restrict__ ph_bd,
                                              int* __restrict__ mel2ph){
  int b = blockIdx.x, tid = threadIdx.x;
  const int* in  = ph_bd  + (size_t)b*TDIM;
  int*       out = mel2ph + (size_t)b*TDIM;
  int base = tid*32;
  int vals[32]; int s=0;
  #pragma unroll
  for (int i=0;i<32;i+=4){
    int4 v = *(const int4*)(in+base+i);
    vals[i]=v.x; vals[i+1]=v.y; vals[i+2]=v.z; vals[i+3]=v.w;
    s += v.x+v.y+v.z+v.w;
  }
  __shared__ int ls[256];
  ls[tid]=s; __syncthreads();
  for (int off=1; off<256; off<<=1){
    int t = (tid>=off)? ls[tid-off] : 0;
    __syncthreads();
    ls[tid]+=t;
    __syncthreads();
  }
  int run = ls[tid]-s;                   // exclusive prefix for this thread
  #pragma unroll
  for (int i=0;i<32;i++){ run += vals[i]; out[base+i]=run; }
}

// ---------------- K_prep: weight transposes (bf16), row offsets, zero pad rows ----
__global__ __launch_bounds__(256) void k_prep(
    const float* __restrict__ conv1_w, const float* __restrict__ conv2_w,
    const float* __restrict__ post_w,
    __bf16* __restrict__ w1t, __bf16* __restrict__ w2t, __bf16* __restrict__ w3t,
    int* __restrict__ rowoff,
    float* __restrict__ x0pad, __bf16* __restrict__ h1pad, __bf16* __restrict__ x2pad)
{
  int idx = blockIdx.x*256 + threadIdx.x;
  if (idx < 256*768){                       // B^T for K=3 convs: [o][k=dl*256+i]
    int o = idx/768, j = idx - o*768;
    int dl = j>>8, i = j&255;
    int src = (o*256+i)*3 + dl;
    w1t[idx] = (__bf16)conv1_w[src];
    w3t[idx] = (__bf16)post_w[src];
  }
  if (idx < 256*256)                        // conv2 1x1: [o][i]
    w2t[idx] = (__bf16)conv2_w[idx];
  if (idx < MROWS){                         // padded-layout element offset of conv window start
    int b = idx/513, l = idx - b*513;
    rowoff[idx] = (b*PADL + l)*HDIM;
  }
  if (idx < BDIM*2*HDIM){                   // zero the 2 pad rows per batch (ws is poisoned)
    int b = idx>>9, rr=(idx>>8)&1, c=idx&255;
    size_t row = (size_t)b*PADL + (rr? (PADL-1):0);
    x0pad[row*HDIM+c]=0.f;
    h1pad[row*HDIM+c]=(__bf16)0.f;
    x2pad[row*HDIM+c]=(__bf16)0.f;
  }
}

// ---------------- K1: fused attn + segment aggregation + nonpad + LN1 -------------
__global__ __launch_bounds__(256) void k_attn_agg(
    const float* __restrict__ feat, const int* __restrict__ mel2ph,
    const float* __restrict__ w_attn, const float* __restrict__ b_attn,
    const float* __restrict__ ln1_g, const float* __restrict__ ln1_b,
    float* __restrict__ x0pad, __bf16* __restrict__ h1pad, float* __restrict__ nonpad)
{
  int b = blockIdx.x / PHL, p = blockIdx.x - b*PHL;
  int tid = threadIdx.x, lane = tid&63, w = tid>>6;
  __shared__ float sfeat[16][HDIM];   // 16 KB frame tile
  __shared__ float sam[16];
  __shared__ float red[4];

  // segment [t0,t1): frames with mel2ph==p (mel2ph nondecreasing)
  const int* row = mel2ph + (size_t)b*TDIM;
  int t0, t1;
  { int lo=0, hi=TDIM; while(lo<hi){ int mid=(lo+hi)>>1; if(row[mid]<p) lo=mid+1; else hi=mid; } t0=lo; }
  { int lo=t0, hi=TDIM; while(lo<hi){ int mid=(lo+hi)>>1; if(row[mid]<p+1) lo=mid+1; else hi=mid; } t1=lo; }

  float wa0[4], wa1[4];
  #pragma unroll
  for (int q=0;q<4;q++){ wa0[q]=w_attn[lane+64*q]; wa1[q]=w_attn[HDIM+lane+64*q]; }
  float ba0=b_attn[0], ba1=b_attn[1];

  float agg=0.f, denom=0.f;
  for (int base=t0; base<t1; base+=16){
    int nf = min(16, t1-base);
    for (int ft=0; ft<nf; ft++)
      sfeat[ft][tid] = feat[((size_t)b*TDIM + base+ft)*HDIM + tid];
    __syncthreads();
    // wave w handles frames w, w+4, ... : dot(feat[t,:], w_attn[a,:]) via wave reduce
    for (int ft=w; ft<nf; ft+=4){
      float d0=0.f, d1=0.f;
      #pragma unroll
      for (int q=0;q<4;q++){ float f=sfeat[ft][lane+64*q]; d0+=f*wa0[q]; d1+=f*wa1[q]; }
      #pragma unroll
      for (int off=32;off>0;off>>=1){ d0+=__shfl_xor(d0,off,64); d1+=__shfl_xor(d1,off,64); }
      if (lane==0) sam[ft] = 0.5f*(sigmoidf_(d0+ba0)+sigmoidf_(d1+ba1));
    }
    __syncthreads();
    for (int ft=0; ft<nf; ft++){ float a=sam[ft]; agg += sfeat[ft][tid]*a; denom += a; }
    __syncthreads();
  }

  float x = agg/(denom+1e-5f);
  float sabs = blk_reduce(fabsf(x), red);
  float np = (sabs>0.f)?1.f:0.f;
  float mean = blk_reduce(x, red)*(1.f/HDIM);
  float d = x-mean;
  float var = blk_reduce(d*d, red)*(1.f/HDIM);
  float h = d*rsqrtf(var+1e-5f)*ln1_g[tid]+ln1_b[tid];

  size_t off = ((size_t)b*PADL + p + 1)*HDIM;
  x0pad[off+tid]=x;
  h1pad[off+tid]=(__bf16)h;
  if (tid==0) nonpad[blockIdx.x]=np;
}

// ---------------- GEMM (bf16 MFMA): 64x64 tile, 256 thr (4 waves, 2x2 of 32x32) ---
// A rows: MODE 0/2 = padded buffer via rowoff (contiguous 768 = im2col K=3 window)
//         MODE 1   = dense [M,256]
// Bt: [N=256][K] bf16.  Epilogues: 0=conv1(+b,*3^-.5,silu)->bf16  1=conv2(+b)->f32
//                                  2=post (+b)*nonpad->bf16
template<int KD, int MODE>
__global__ __launch_bounds__(256) void k_gemm(
    const short* __restrict__ A, const int* __restrict__ rowoff,
    const short* __restrict__ Bt, const float* __restrict__ bias,
    const float* __restrict__ nonpad, void* __restrict__ outp)
{
  __shared__ short As[64][40];   // [m][k] pad-> stride 80B (2-way LDS alias, free)
  __shared__ short Bs[64][40];   // [n][k]
  int tid = threadIdx.x;
  int m0 = blockIdx.x*64, n0 = blockIdx.y*64;

  int ar  = tid>>2, av8 = (tid&3)*8;      // staging: 1 row-chunk of 8 elems / thread
  int am  = m0 + ar;
  bool avalid = am < MROWS;
  const short* aptr;
  if (MODE==1) aptr = A + (size_t)(avalid? am:0)*HDIM;
  else         aptr = A + (avalid? rowoff[am] : 0);
  const short* bptr = Bt + (size_t)(n0 + ar)*KD;

  int lane=tid&63, w=tid>>6;
  int wm=(w>>1)*32, wn=(w&1)*32, quad=lane>>4, l15=lane&15;

  floatx4 acc[2][2] = {};
  for (int k0=0;k0<KD;k0+=32){
    short8 a8 = {0,0,0,0,0,0,0,0};
    if (avalid) a8 = *(const short8*)(aptr + k0 + av8);
    short8 b8 = *(const short8*)(bptr + k0 + av8);
    __syncthreads();                      // prev iter's frag reads done
    *(short8*)&As[ar][av8] = a8;
    *(short8*)&Bs[ar][av8] = b8;
    __syncthreads();
    short8 af[2], bfr[2];
    #pragma unroll
    for (int t=0;t<2;t++){
      af[t]  = *(const short8*)&As[wm + t*16 + l15][quad*8];
      bfr[t] = *(const short8*)&Bs[wn + t*16 + l15][quad*8];
    }
    #pragma unroll
    for (int ti=0;ti<2;ti++)
      #pragma unroll
      for (int tj=0;tj<2;tj++)
        acc[ti][tj] = __builtin_amdgcn_mfma_f32_16x16x32_bf16(af[ti], bfr[tj], acc[ti][tj], 0,0,0);
  }
  // D layout: row=(lane>>4)*4+reg, col=lane&15  (verified m89/m91)
  #pragma unroll
  for (int ti=0;ti<2;ti++){
    int mb = m0 + wm + ti*16 + quad*4;
    #pragma unroll
    for (int tj=0;tj<2;tj++){
      int n = n0 + wn + tj*16 + l15;
      #pragma unroll
      for (int r=0;r<4;r++){
        int mm = mb + r;
        if (mm < MROWS){
          float v = acc[ti][tj][r] + bias[n];
          if (MODE==0){
            v *= 0.57735026918962576f;          // 3^-0.5
            v  = v * sigmoidf_(v);              // silu
            ((__bf16*)outp)[(size_t)mm*HDIM+n] = (__bf16)v;
          } else if (MODE==1){
            ((float*)outp)[(size_t)mm*HDIM+n] = v;
          } else {
            v *= nonpad[mm];
            ((__bf16*)outp)[(size_t)mm*HDIM+n] = (__bf16)v;
          }
        }
      }
    }
  }
}

// ---------------- K3b: residual + nonpad + LN2 -> x2pad (bf16, padded) ------------
__global__ __launch_bounds__(256) void k_resid_ln2(
    const float* __restrict__ x0pad, const float* __restrict__ h2,
    const int* __restrict__ rowoff, const float* __restrict__ nonpad,
    const float* __restrict__ g2, const float* __restrict__ b2,
    __bf16* __restrict__ x2pad)
{
  __shared__ float red[4];
  int r = blockIdx.x, tid = threadIdx.x;
  int off = rowoff[r] + HDIM;            // data row (pad-skip)
  float np = nonpad[r];
  float x = (x0pad[off+tid] + h2[(size_t)r*HDIM+tid]) * np;
  float mean = blk_reduce(x, red)*(1.f/HDIM);
  float d = x-mean;
  float var = blk_reduce(d*d, red)*(1.f/HDIM);
  x2pad[off+tid] = (__bf16)((d*rsqrtf(var+1e-5f)*g2[tid]+b2[tid])*np);
}

// ---------------- K5: logits = out @ w_out^T + b_out (wave per row) ---------------
__global__ __launch_bounds__(256) void k_logits(
    const __bf16* __restrict__ outb, const float* __restrict__ w_out,
    const float* __restrict__ b_out, float* __restrict__ dst)
{
  int r = blockIdx.x*4 + (threadIdx.x>>6);
  int lane = threadIdx.x & 63;
  float x[4];
  #pragma unroll
  for (int q=0;q<4;q++) x[q] = (float)outb[(size_t)r*HDIM + lane + 64*q];
  float p[5];
  #pragma unroll
  for (int o=0;o<5;o++){
    float s=0.f;
    #pragma unroll
    for (int q=0;q<4;q++) s += x[q]*w_out[o*HDIM+lane+64*q];
    #pragma unroll
    for (int off=32;off>0;off>>=1) s += __shfl_xor(s,off,64);
    p[o]=s;
  }
  if (lane==0){
    #pragma unroll
    for (int o=0;o<5;o++) dst[(size_t)r*5+o] = p[o] + b_out[o];
  }
}

extern "C" void kernel_launch(void* const* d_in, const int* in_sizes, int n_in,
                              void* d_out, int out_size, void* d_ws, size_t ws_size,
                              hipStream_t stream) {
  const float* feat    = (const float*)d_in[0];
  const int*   ph_bd   = (const int*)  d_in[1];
  // d_in[2] = ph_length scalar (513, hardcoded)
  const float* w_attn  = (const float*)d_in[3];
  const float* b_attn  = (const float*)d_in[4];
  const float* ln1_g   = (const float*)d_in[5];
  const float* ln1_b   = (const float*)d_in[6];
  const float* conv1_w = (const float*)d_in[7];
  const float* conv1_b = (const float*)d_in[8];
  const float* conv2_w = (const float*)d_in[9];
  const float* conv2_b = (const float*)d_in[10];
  const float* ln2_g   = (const float*)d_in[11];
  const float* ln2_b   = (const float*)d_in[12];
  const float* post_w  = (const float*)d_in[13];
  const float* post_b  = (const float*)d_in[14];
  const float* w_out   = (const float*)d_in[15];
  const float* b_out   = (const float*)d_in[16];

  char* wp = (char*)d_ws;
  auto alloc = [&](size_t bytes)->void*{
    void* p = (void*)wp; wp += (bytes + 255) & ~(size_t)255; return p;
  };
  int*    mel2ph = (int*)   alloc((size_t)BDIM*TDIM*4);
  int*    rowoff = (int*)   alloc((size_t)MROWS*4);
  float*  x0pad  = (float*) alloc((size_t)BDIM*PADL*HDIM*4);
  __bf16* h1pad  = (__bf16*)alloc((size_t)BDIM*PADL*HDIM*2);
  __bf16* g      = (__bf16*)alloc((size_t)MROWS*HDIM*2);
  float*  h2     = (float*) alloc((size_t)MROWS*HDIM*4);
  __bf16* x2pad  = (__bf16*)alloc((size_t)BDIM*PADL*HDIM*2);
  __bf16* outb   = (__bf16*)alloc((size_t)MROWS*HDIM*2);
  float*  nonpad = (float*) alloc((size_t)MROWS*4);
  __bf16* w1t    = (__bf16*)alloc((size_t)256*768*2);
  __bf16* w2t    = (__bf16*)alloc((size_t)256*256*2);
  __bf16* w3t    = (__bf16*)alloc((size_t)256*768*2);

  k_scan<<<BDIM, 256, 0, stream>>>(ph_bd, mel2ph);
  k_prep<<<768, 256, 0, stream>>>(conv1_w, conv2_w, post_w, w1t, w2t, w3t,
                                  rowoff, x0pad, h1pad, x2pad);
  k_attn_agg<<<MROWS, 256, 0, stream>>>(feat, mel2ph, w_attn, b_attn,
                                        ln1_g, ln1_b, x0pad, h1pad, nonpad);
  dim3 gg(129, 4);
  k_gemm<768,0><<<gg, 256, 0, stream>>>((const short*)h1pad, rowoff, (const short*)w1t,
                                        conv1_b, nullptr, (void*)g);
  k_gemm<256,1><<<gg, 256, 0, stream>>>((const short*)g, rowoff, (const short*)w2t,
                                        conv2_b, nullptr, (void*)h2);
  k_resid_ln2<<<MROWS, 256, 0, stream>>>(x0pad, h2, rowoff, nonpad, ln2_g, ln2_b, x2pad);
  k_gemm<768,2><<<gg, 256, 0, stream>>>((const short*)x2pad, rowoff, (const short*)w3t,
                                        post_b, nonpad, (void*)outb);
  k_logits<<<MROWS/4, 256, 0, stream>>>(outb, w_out, b_out, (float*)d_out);
}